// Round 6
// baseline (1163.848 us; speedup 1.0000x reference)
//
#include <hip/hip_runtime.h>
#include <hip/hip_fp16.h>
#include <math.h>

#define DEV static __device__ __forceinline__

namespace {
constexpr int S  = 2048;
constexpr int D  = 768;
constexpr int Hh = 12;
constexpr int DK = 64;
constexpr int F  = 3072;
constexpr int Nn = 4096;
constexpr int FEAT = 9;            // 1 silu + 8 spline
constexpr int K1   = D * FEAT;     // 6912
constexpr int LDAB = 6912;         // row stride of feat / packed W (elements)
}

typedef _Float16 half8 __attribute__((ext_vector_type(8)));
typedef float f32x4 __attribute__((ext_vector_type(4)));

// global -> LDS direct copy, 16B/lane, LDS dest = wave-uniform base + lane*16
DEV void gld16(const void* g, void* l) {
    __builtin_amdgcn_global_load_lds((__attribute__((address_space(1))) void*)g,
                                     (__attribute__((address_space(3))) void*)l,
                                     16, 0, 0);
}

// bijective XCD swizzle (m204): each XCD gets a contiguous id range
DEV int xcd_swz(int id, int nwg) {
    int q = nwg >> 3, r = nwg & 7;
    int xcd = id & 7, pos = id >> 3;
    return (xcd < r ? xcd * (q + 1) : r * (q + 1) + (xcd - r) * q) + pos;
}

// ------- feature eval: silu + 8 cubic B-spline bases (validated r2-r5) ----
DEV void features9(float xv, float* f) {
    f[0] = xv / (1.0f + __expf(-xv));
    float sp = (xv + 2.2f) * 2.5f;
    float fj = floorf(sp);
    int j = (int)fj;
    float u = sp - fj;
    float u2 = u * u, u3 = u2 * u;
    float omu = 1.0f - u;
    float b0 = (1.0f / 6.0f) * omu * omu * omu;
    float b1 = 0.5f * u3 - u2 + (2.0f / 3.0f);
    float b2 = -0.5f * u3 + 0.5f * u2 + 0.5f * u + (1.0f / 6.0f);
    float b3 = (1.0f / 6.0f) * u3;
#pragma unroll
    for (int m = 0; m < 8; ++m) {
        int d = j - m;
        f[1 + m] = (d == 3) ? b0 : (d == 2) ? b1 : (d == 1) ? b2 : (d == 0) ? b3 : 0.0f;
    }
}

// ---------------- LN1: fp32 in -> fp16 out --------------------------------
__global__ __launch_bounds__(256) void ln16_kernel(const float* __restrict__ x,
                                                   const float* __restrict__ g,
                                                   const float* __restrict__ bta,
                                                   _Float16* __restrict__ y) {
    int row = blockIdx.x;
    const float* xr = x + (size_t)row * D;
    _Float16* yr = y + (size_t)row * D;
    int t = threadIdx.x;
    float v[3];
#pragma unroll
    for (int j = 0; j < 3; ++j) v[j] = xr[t + j * 256];
    float s = v[0] + v[1] + v[2];
#pragma unroll
    for (int o = 1; o < 64; o <<= 1) s += __shfl_xor(s, o, 64);
    __shared__ float red[4], red2[4];
    int wid = t >> 6;
    if ((t & 63) == 0) red[wid] = s;
    __syncthreads();
    float mean = (red[0] + red[1] + red[2] + red[3]) * (1.0f / 768.0f);
    float d0 = v[0] - mean, d1 = v[1] - mean, d2 = v[2] - mean;
    float sq = d0 * d0 + d1 * d1 + d2 * d2;
#pragma unroll
    for (int o = 1; o < 64; o <<= 1) sq += __shfl_xor(sq, o, 64);
    if ((t & 63) == 0) red2[wid] = sq;
    __syncthreads();
    float var = (red2[0] + red2[1] + red2[2] + red2[3]) * (1.0f / 768.0f);
    float rstd = rsqrtf(var + 1e-5f);
#pragma unroll
    for (int j = 0; j < 3; ++j) {
        int c = t + j * 256;
        yr[c] = (_Float16)((v[j] - mean) * rstd * g[c] + bta[c]);
    }
}

// ------- LN2 of (x + attn) fused with feature expansion -> feat1 ----------
__global__ __launch_bounds__(256) void ln_feat(const float* __restrict__ xa,
                                               const float* __restrict__ xb,
                                               const float* __restrict__ g,
                                               const float* __restrict__ bta,
                                               _Float16* __restrict__ feat) {
    int row = blockIdx.x;
    const float* xar = xa + (size_t)row * D;
    const float* xbr = xb + (size_t)row * D;
    int t = threadIdx.x;
    float v[3];
#pragma unroll
    for (int j = 0; j < 3; ++j) v[j] = xar[t + j * 256] + xbr[t + j * 256];
    float s = v[0] + v[1] + v[2];
#pragma unroll
    for (int o = 1; o < 64; o <<= 1) s += __shfl_xor(s, o, 64);
    __shared__ float red[4], red2[4];
    __shared__ __align__(16) _Float16 fbuf[K1];
    int wid = t >> 6;
    if ((t & 63) == 0) red[wid] = s;
    __syncthreads();
    float mean = (red[0] + red[1] + red[2] + red[3]) * (1.0f / 768.0f);
    float d0 = v[0] - mean, d1 = v[1] - mean, d2 = v[2] - mean;
    float sq = d0 * d0 + d1 * d1 + d2 * d2;
#pragma unroll
    for (int o = 1; o < 64; o <<= 1) sq += __shfl_xor(sq, o, 64);
    if ((t & 63) == 0) red2[wid] = sq;
    __syncthreads();
    float var = (red2[0] + red2[1] + red2[2] + red2[3]) * (1.0f / 768.0f);
    float rstd = rsqrtf(var + 1e-5f);
#pragma unroll
    for (int j = 0; j < 3; ++j) {
        int c = t + j * 256;
        float y = (v[j] - mean) * rstd * g[c] + bta[c];
        float f[9];
        features9(y, f);
#pragma unroll
        for (int cc = 0; cc < 9; ++cc) fbuf[c * 9 + cc] = (_Float16)f[cc];
    }
    __syncthreads();
    _Float16* dst = feat + (size_t)row * K1;
    for (int i = t; i < K1 / 8; i += 256)
        *(half8*)(dst + i * 8) = *(const half8*)&fbuf[i * 8];
}

// ------- feature expansion of h1 chunk (768 cols) -> featbuf --------------
__global__ __launch_bounds__(256) void feat2_chunk(const _Float16* __restrict__ h1,
                                                   int c0,
                                                   _Float16* __restrict__ feat) {
    int row = blockIdx.x;
    int t = threadIdx.x;
    __shared__ __align__(16) _Float16 fbuf[K1];
    const _Float16* src = h1 + (size_t)row * F + c0;
#pragma unroll
    for (int j = 0; j < 3; ++j) {
        int ic = t + j * 256;
        float y = (float)src[ic];
        float f[9];
        features9(y, f);
#pragma unroll
        for (int cc = 0; cc < 9; ++cc) fbuf[ic * 9 + cc] = (_Float16)f[cc];
    }
    __syncthreads();
    _Float16* dst = feat + (size_t)row * K1;
    for (int i = t; i < K1 / 8; i += 256)
        *(half8*)(dst + i * 8) = *(const half8*)&fbuf[i * 8];
}

// ------- pack KAN weights: Wp[o][ic*9+c] = {base_w, spline*scaler} fp16 ---
__global__ __launch_bounds__(256) void prep_w(const float* __restrict__ bw,
                                              const float* __restrict__ sw,
                                              const float* __restrict__ scal,
                                              _Float16* __restrict__ Wp,
                                              int INfull, int c0) {
    int o = blockIdx.y;
    int ic = blockIdx.x * 256 + threadIdx.x;
    size_t idx = (size_t)o * INfull + c0 + ic;
    float bwv = bw[idx];
    float sc  = scal[idx];
    float4 s0 = *(const float4*)(sw + idx * 8);
    float4 s1 = *(const float4*)(sw + idx * 8 + 4);
    _Float16* dst = Wp + ((size_t)o * 768 + ic) * 9;
    dst[0] = (_Float16)bwv;
    dst[1] = (_Float16)(s0.x * sc);
    dst[2] = (_Float16)(s0.y * sc);
    dst[3] = (_Float16)(s0.z * sc);
    dst[4] = (_Float16)(s0.w * sc);
    dst[5] = (_Float16)(s1.x * sc);
    dst[6] = (_Float16)(s1.y * sc);
    dst[7] = (_Float16)(s1.z * sc);
    dst[8] = (_Float16)(s1.w * sc);
}

// ---------------- prep: qkv weights fp32 -> fp16 --------------------------
__global__ __launch_bounds__(256) void prep_qkv(const float* __restrict__ wq,
                                                const float* __restrict__ wk,
                                                const float* __restrict__ wv,
                                                _Float16* __restrict__ Wh) {
    int idx = blockIdx.x * 256 + threadIdx.x;
    const int per = D * D;
    if (idx >= 3 * per) return;
    int z = idx / per, rem = idx - z * per;
    const float* w = (z == 0) ? wq : (z == 1) ? wk : wv;
    Wh[idx] = (_Float16)w[rem];
}

// ---------------- QKV via fp16 MFMA, writes (B,H,S,DK) fp16 ---------------
__global__ __launch_bounds__(256, 2) void qkv16(const _Float16* __restrict__ Xh,
                                                const _Float16* __restrict__ Wh,
                                                const float* __restrict__ bq,
                                                const float* __restrict__ bk,
                                                const float* __restrict__ bv,
                                                _Float16* __restrict__ q,
                                                _Float16* __restrict__ k,
                                                _Float16* __restrict__ v) {
    // XCD-swizzled, M-major decode (consecutive ids share the B weight panel)
    int nb = gridDim.x, mb = gridDim.y;
    int nwg = nb * mb * gridDim.z;
    int id = blockIdx.x + nb * (blockIdx.y + mb * blockIdx.z);
    int id2 = xcd_swz(id, nwg);
    int z = id2 / (nb * mb);
    int rem = id2 % (nb * mb);
    int m0 = (rem % mb) * 128, o0 = (rem / mb) * 128;

    const _Float16* W = Wh + (size_t)z * D * D;
    const float* bias = (z == 0) ? bq : (z == 1) ? bk : bv;
    _Float16* out     = (z == 0) ? q  : (z == 1) ? k  : v;

    __shared__ __align__(16) _Float16 As[128][72];
    int t = threadIdx.x;
    int l = t & 63, w = t >> 6;
    int wr = (w >> 1) * 64, wc = (w & 1) * 64;
    int lm = l & 15, lk = (l >> 4) * 8;
    int srow = t >> 1, sh = t & 1;

    f32x4 acc[4][4];
#pragma unroll
    for (int a = 0; a < 4; ++a)
#pragma unroll
        for (int b = 0; b < 4; ++b)
#pragma unroll
            for (int c = 0; c < 4; ++c) acc[a][b][c] = 0.0f;

    const _Float16* bp0 = W + (size_t)(o0 + wc + lm) * D + lk;

    for (int kt = 0; kt < D / 64; ++kt) {
        half8 ar[4];
#pragma unroll
        for (int i = 0; i < 4; ++i)
            ar[i] = *(const half8*)(Xh + (size_t)(m0 + srow) * D + kt * 64 + sh * 32 + i * 8);
        __syncthreads();
#pragma unroll
        for (int i = 0; i < 4; ++i)
            *(half8*)&As[srow][sh * 32 + i * 8] = ar[i];
        __syncthreads();
        half8 bfr[2][4];
#pragma unroll
        for (int kc = 0; kc < 2; ++kc)
#pragma unroll
            for (int nf = 0; nf < 4; ++nf)
                bfr[kc][nf] = *(const half8*)(bp0 + (size_t)nf * 16 * D + kt * 64 + kc * 32);
#pragma unroll
        for (int kc = 0; kc < 2; ++kc) {
            half8 a_[4];
#pragma unroll
            for (int mf = 0; mf < 4; ++mf)
                a_[mf] = *(const half8*)&As[wr + mf * 16 + lm][kc * 32 + lk];
#pragma unroll
            for (int mf = 0; mf < 4; ++mf)
#pragma unroll
                for (int nf = 0; nf < 4; ++nf)
                    acc[mf][nf] = __builtin_amdgcn_mfma_f32_16x16x32_f16(a_[mf], bfr[kc][nf], acc[mf][nf], 0, 0, 0);
        }
    }
    int r0 = m0 + wr + (l >> 4) * 4;
    int c0 = o0 + wc + lm;
#pragma unroll
    for (int mf = 0; mf < 4; ++mf)
#pragma unroll
        for (int nf = 0; nf < 4; ++nf) {
            int col = c0 + nf * 16;
            int hh = col >> 6, dd = col & 63;
            float bv_ = bias[col];
#pragma unroll
            for (int r = 0; r < 4; ++r) {
                int n = r0 + mf * 16 + r;
                int b = n >> 11, ss = n & 2047;
                out[(((size_t)(b * Hh + hh) * S + ss) * DK + dd)] = (_Float16)(acc[mf][nf][r] + bv_);
            }
        }
}

// ---------------- Flash attention, fp16 MFMA ------------------------------
// 128 q-rows/block, 8 waves x 16 rows; K-tiles of 64 keys.
// K staged by waves 0-3, V (transposed) by waves 4-7 in parallel.
__global__ __launch_bounds__(512) void attn16(const _Float16* __restrict__ q16,
                                              const _Float16* __restrict__ k16,
                                              const _Float16* __restrict__ v16,
                                              float* __restrict__ attno) {
    int nwg = gridDim.x * gridDim.y;          // 16 * 24
    int id = blockIdx.x + gridDim.x * blockIdx.y;
    int id2 = xcd_swz(id, nwg);
    int bh = id2 / gridDim.x;                 // consecutive ids share (b,h) K/V
    int q0 = (id2 % gridDim.x) * 128;

    int t = threadIdx.x;
    int l = t & 63, w = t >> 6;
    int lm = l & 15, lk = (l >> 4) * 8;
    int wr = w * 16;                          // wave's q-row base

    __shared__ __align__(16) _Float16 Qs[128][72];
    __shared__ __align__(16) _Float16 Ps[128][72];
    __shared__ __align__(16) _Float16 Ks[64][72];
    __shared__ __align__(16) _Float16 Vt[64][72];   // [d][key]

    const _Float16* qb = q16 + ((size_t)bh * S + q0) * DK;
    const _Float16* kb = k16 + (size_t)bh * S * DK;
    const _Float16* vb = v16 + (size_t)bh * S * DK;

    {   // stage Q once, fold 1/8 score scale (exact in fp16)
        int row = t >> 2, dg = t & 3;
        half8 h0 = *(const half8*)(qb + row * DK + dg * 16);
        half8 h1 = *(const half8*)(qb + row * DK + dg * 16 + 8);
#pragma unroll
        for (int j = 0; j < 8; ++j) { h0[j] = h0[j] * (_Float16)0.125f; h1[j] = h1[j] * (_Float16)0.125f; }
        *(half8*)&Qs[row][dg * 16] = h0;
        *(half8*)&Qs[row][dg * 16 + 8] = h1;
    }

    float m_[4], l_[4];
    f32x4 oacc[4];
#pragma unroll
    for (int r = 0; r < 4; ++r) { m_[r] = -INFINITY; l_[r] = 0.0f; }
#pragma unroll
    for (int nf = 0; nf < 4; ++nf)
#pragma unroll
        for (int r = 0; r < 4; ++r) oacc[nf][r] = 0.0f;

    for (int kt = 0; kt < S / 64; ++kt) {
        __syncthreads();   // prev tile consumed (covers Q stage at kt=0)
        {
            int tt = t & 255;
            int key = tt & 63, dg = tt >> 6;
            if (t < 256) {
                const _Float16* kr = kb + ((size_t)kt * 64 + key) * DK + dg * 16;
                half8 k0 = *(const half8*)(kr);
                half8 k1 = *(const half8*)(kr + 8);
                *(half8*)&Ks[key][dg * 16] = k0;
                *(half8*)&Ks[key][dg * 16 + 8] = k1;
            } else {
                const _Float16* vr = vb + ((size_t)kt * 64 + key) * DK + dg * 16;
                half8 v0 = *(const half8*)(vr);
                half8 v1 = *(const half8*)(vr + 8);
#pragma unroll
                for (int j = 0; j < 8; ++j) {
                    Vt[dg * 16 + j][key] = v0[j];
                    Vt[dg * 16 + 8 + j][key] = v1[j];
                }
            }
        }
        __syncthreads();

        // S = Q K^T (scaled): wave's 16 rows x 64 keys
        f32x4 sc[4];
#pragma unroll
        for (int nf = 0; nf < 4; ++nf)
#pragma unroll
            for (int r = 0; r < 4; ++r) sc[nf][r] = 0.0f;
        __builtin_amdgcn_s_setprio(1);
#pragma unroll
        for (int kc = 0; kc < 2; ++kc) {
            half8 aq = *(const half8*)&Qs[wr + lm][kc * 32 + lk];
#pragma unroll
            for (int nf = 0; nf < 4; ++nf) {
                half8 bk8 = *(const half8*)&Ks[nf * 16 + lm][kc * 32 + lk];
                sc[nf] = __builtin_amdgcn_mfma_f32_16x16x32_f16(aq, bk8, sc[nf], 0, 0, 0);
            }
        }
        __builtin_amdgcn_s_setprio(0);
        // online softmax; lane's rows: wr + (l>>4)*4 + r
        float pmax[4];
#pragma unroll
        for (int r = 0; r < 4; ++r) {
            pmax[r] = fmaxf(fmaxf(sc[0][r], sc[1][r]), fmaxf(sc[2][r], sc[3][r]));
#pragma unroll
            for (int mk = 1; mk < 16; mk <<= 1)
                pmax[r] = fmaxf(pmax[r], __shfl_xor(pmax[r], mk, 64));
        }
        float corr[4], rs[4];
#pragma unroll
        for (int r = 0; r < 4; ++r) {
            float mnew = fmaxf(m_[r], pmax[r]);
            corr[r] = __expf(m_[r] - mnew);
            m_[r] = mnew;
            rs[r] = 0.0f;
        }
#pragma unroll
        for (int nf = 0; nf < 4; ++nf)
#pragma unroll
            for (int r = 0; r < 4; ++r) {
                float p = __expf(sc[nf][r] - m_[r]);
                sc[nf][r] = p;
                rs[r] += p;
            }
#pragma unroll
        for (int r = 0; r < 4; ++r) {
#pragma unroll
            for (int mk = 1; mk < 16; mk <<= 1)
                rs[r] += __shfl_xor(rs[r], mk, 64);
            l_[r] = l_[r] * corr[r] + rs[r];
        }
        // P -> LDS fp16 (wave-private rows), rescale O
        int pr = wr + (l >> 4) * 4;
#pragma unroll
        for (int nf = 0; nf < 4; ++nf)
#pragma unroll
            for (int r = 0; r < 4; ++r)
                Ps[pr + r][nf * 16 + lm] = (_Float16)sc[nf][r];
#pragma unroll
        for (int nf = 0; nf < 4; ++nf)
#pragma unroll
            for (int r = 0; r < 4; ++r) oacc[nf][r] *= corr[r];
        // O += P V
        __builtin_amdgcn_s_setprio(1);
#pragma unroll
        for (int kc = 0; kc < 2; ++kc) {
            half8 ap = *(const half8*)&Ps[wr + lm][kc * 32 + lk];
#pragma unroll
            for (int nf = 0; nf < 4; ++nf) {
                half8 bv8 = *(const half8*)&Vt[nf * 16 + lm][kc * 32 + lk];
                oacc[nf] = __builtin_amdgcn_mfma_f32_16x16x32_f16(ap, bv8, oacc[nf], 0, 0, 0);
            }
        }
        __builtin_amdgcn_s_setprio(0);
    }
    int b = bh / Hh, hh = bh % Hh;
    int pr = wr + (l >> 4) * 4;
#pragma unroll
    for (int r = 0; r < 4; ++r) {
        float inv = 1.0f / l_[r];
        float* orow = attno + ((size_t)b * S + q0 + pr + r) * D + hh * DK;
#pragma unroll
        for (int nf = 0; nf < 4; ++nf)
            orow[nf * 16 + lm] = oacc[nf][r] * inv;
    }
}

// ---------------- pure fp16 GEMM (m97 structure): C = A * B^T -------------
// 128x128 tile, 4 waves x (64x64), BK=64, global_load_lds staging.
// XCD-swizzled M-major grid: consecutive ids share the B-panel (L2-resident).
template <int KS, bool TOF16>
__global__ __launch_bounds__(256) void kan_gemm(const _Float16* __restrict__ A,
                                                const _Float16* __restrict__ B,
                                                _Float16* __restrict__ out16,
                                                float* __restrict__ out32,
                                                int O, int accum) {
    __shared__ __align__(16) _Float16 Al[128 * 64];
    __shared__ __align__(16) _Float16 Bl[128 * 64];
    int nb = gridDim.x, mb = gridDim.y;
    int nwg = nb * mb * gridDim.z;
    int id = blockIdx.x + nb * (blockIdx.y + mb * blockIdx.z);
    int id2 = xcd_swz(id, nwg);
    int slot = id2 / (nb * mb);
    int rem = id2 % (nb * mb);
    int m0 = (rem % mb) * 128, o0 = (rem / mb) * 128;

    int t = threadIdx.x;
    int l = t & 63, w = t >> 6;
    int wr = (w >> 1) * 64, wc = (w & 1) * 64;
    int lm = l & 15, lk = (l >> 4) * 8;

    const _Float16* Ab = A + (size_t)slot * KS * 64;
    const _Float16* Bb = B + (size_t)slot * KS * 64;
    int srow = l >> 3, scol = (l & 7) * 8;

    f32x4 acc[4][4];
#pragma unroll
    for (int a = 0; a < 4; ++a)
#pragma unroll
        for (int b = 0; b < 4; ++b)
#pragma unroll
            for (int c = 0; c < 4; ++c) acc[a][b][c] = 0.0f;

    for (int kt = 0; kt < KS; ++kt) {
        if (kt) __syncthreads();
        size_t kofs = (size_t)kt * 64 + scol;
#pragma unroll
        for (int j = 0; j < 4; ++j) {
            int row = w * 32 + j * 8;
            gld16(Ab + (size_t)(m0 + row + srow) * LDAB + kofs, &Al[row * 64]);
            gld16(Bb + (size_t)(o0 + row + srow) * LDAB + kofs, &Bl[row * 64]);
        }
        __syncthreads();
#pragma unroll
        for (int kc = 0; kc < 2; ++kc) {
            half8 af[4], bf[4];
#pragma unroll
            for (int mf = 0; mf < 4; ++mf)
                af[mf] = *(const half8*)&Al[(wr + mf * 16 + lm) * 64 + kc * 32 + lk];
#pragma unroll
            for (int nf = 0; nf < 4; ++nf)
                bf[nf] = *(const half8*)&Bl[(wc + nf * 16 + lm) * 64 + kc * 32 + lk];
#pragma unroll
            for (int mf = 0; mf < 4; ++mf)
#pragma unroll
                for (int nf = 0; nf < 4; ++nf)
                    acc[mf][nf] = __builtin_amdgcn_mfma_f32_16x16x32_f16(af[mf], bf[nf], acc[mf][nf], 0, 0, 0);
        }
    }
    int r0 = m0 + wr + (l >> 4) * 4;
    int c0 = o0 + wc + lm;
#pragma unroll
    for (int mf = 0; mf < 4; ++mf)
#pragma unroll
        for (int nf = 0; nf < 4; ++nf)
#pragma unroll
            for (int r = 0; r < 4; ++r) {
                int row = r0 + mf * 16 + r;
                int col = c0 + nf * 16;
                if constexpr (TOF16) {
                    out16[(size_t)row * O + col] = (_Float16)acc[mf][nf][r];
                } else {
                    float* po = out32 + ((size_t)slot * Nn + row) * O + col;
                    float vv = acc[mf][nf][r];
                    if (accum) vv += *po;
                    *po = vv;
                }
            }
}

// ---------------- final reduce: 4 partials + x + attn ---------------------
__global__ __launch_bounds__(256) void reduce4(const float* __restrict__ part,
                                               const float* __restrict__ x,
                                               const float* __restrict__ attno,
                                               float* __restrict__ out) {
    int i = blockIdx.x * 256 + threadIdx.x;
    const size_t ND4 = (size_t)Nn * D / 4;
    if (i >= (int)ND4) return;
    const float4* p0 = (const float4*)part;
    const float4* p1 = p0 + ND4;
    const float4* p2 = p1 + ND4;
    const float4* p3 = p2 + ND4;
    float4 a = p0[i], b = p1[i], c = p2[i], d = p3[i];
    float4 xe = ((const float4*)x)[i], at = ((const float4*)attno)[i];
    float4 o;
    o.x = a.x + b.x + c.x + d.x + xe.x + at.x;
    o.y = a.y + b.y + c.y + d.y + xe.y + at.y;
    o.z = a.z + b.z + c.z + d.z + xe.z + at.z;
    o.w = a.w + b.w + c.w + d.w + xe.w + at.w;
    ((float4*)out)[i] = o;
}

// ---------------- launcher -------------------------------------------------
extern "C" void kernel_launch(void* const* d_in, const int* in_sizes, int n_in,
                              void* d_out, int out_size, void* d_ws, size_t ws_size,
                              hipStream_t stream) {
    const float* x    = (const float*)d_in[0];
    const float* ln1g = (const float*)d_in[2];
    const float* ln1b = (const float*)d_in[3];
    const float* wq   = (const float*)d_in[4];
    const float* bq   = (const float*)d_in[5];
    const float* wk   = (const float*)d_in[6];
    const float* bk   = (const float*)d_in[7];
    const float* wv   = (const float*)d_in[8];
    const float* bv   = (const float*)d_in[9];
    const float* ln2g = (const float*)d_in[10];
    const float* ln2b = (const float*)d_in[11];
    const float* bw1  = (const float*)d_in[12];
    const float* sw1  = (const float*)d_in[13];
    const float* sc1  = (const float*)d_in[14];
    const float* bw2  = (const float*)d_in[15];
    const float* sw2  = (const float*)d_in[16];
    const float* sc2  = (const float*)d_in[17];

    const size_t ND = (size_t)Nn * D;
    char* base = (char*)d_ws;
    _Float16* featbuf = (_Float16*)base;                              // Nn*K1 = 56.6MB
    _Float16* q16 = featbuf;
    _Float16* k16 = featbuf + ND;
    _Float16* v16 = featbuf + 2 * ND;
    char* p = base + (size_t)Nn * K1 * 2;
    float* attno = (float*)p;            p += ND * 4;                 // 12.58MB
    _Float16* h1h = (_Float16*)p;        p += (size_t)Nn * F * 2;     // 25.17MB
    char* R3 = p;
    _Float16* Wp1 = (_Float16*)R3;                                    // 42.5MB
    _Float16* xnh = (_Float16*)(R3 + 42467328);
    _Float16* Wh  = (_Float16*)(R3 + 48758784);
    float* part   = (float*)R3;                                       // 50.3MB (after L1)
    char* R4 = R3 + 52297728;
    _Float16* Wp2c = (_Float16*)R4;                                   // 10.6MB

    // 1. LN1 -> fp16
    ln16_kernel<<<Nn, 256, 0, stream>>>(x, ln1g, ln1b, xnh);
    // 2. qkv weights fp16
    prep_qkv<<<(3 * D * D + 255) / 256, 256, 0, stream>>>(wq, wk, wv, Wh);
    // 3. QKV -> fp16 (B,H,S,DK)
    qkv16<<<dim3(D / 128, Nn / 128, 3), 256, 0, stream>>>(xnh, Wh, bq, bk, bv, q16, k16, v16);
    // 4. flash attention (MFMA, 128-row tiles) -> attno fp32
    attn16<<<dim3(S / 128, 2 * Hh), 512, 0, stream>>>(q16, k16, v16, attno);
    // 5. pack layer-1 weights
    prep_w<<<dim3(3, F), 256, 0, stream>>>(bw1, sw1, sc1, Wp1, D, 0);
    // 6. LN2(x+attn) + feature expansion -> feat1 (overwrites q/k/v)
    ln_feat<<<Nn, 256, 0, stream>>>(x, attno, ln2g, ln2b, featbuf);
    // 7. KAN layer 1 GEMM: (4096x6912) x (3072x6912)^T -> h1h fp16
    kan_gemm<108, true><<<dim3(F / 128, Nn / 128, 1), 256, 0, stream>>>(
        featbuf, Wp1, h1h, nullptr, F, 0);
    // 8. KAN layer 2 in 4 K-chunks; split-K z=4 within chunk
    for (int c = 0; c < 4; ++c) {
        prep_w<<<dim3(3, D), 256, 0, stream>>>(bw2, sw2, sc2, Wp2c, F, c * 768);
        feat2_chunk<<<Nn, 256, 0, stream>>>(h1h, c * 768, featbuf);
        kan_gemm<27, false><<<dim3(D / 128, Nn / 128, 4), 256, 0, stream>>>(
            featbuf, Wp2c, nullptr, part, D, c > 0);
    }
    // 9. partials + residuals -> out
    reduce4<<<(int)(ND / 4 / 256), 256, 0, stream>>>(part, x, attno, (float*)d_out);
}

// Round 7
// 1149.007 us; speedup vs baseline: 1.0129x; 1.0129x over previous
//
#include <hip/hip_runtime.h>
#include <hip/hip_fp16.h>
#include <math.h>

#define DEV static __device__ __forceinline__

namespace {
constexpr int S  = 2048;
constexpr int D  = 768;
constexpr int Hh = 12;
constexpr int DK = 64;
constexpr int F  = 3072;
constexpr int Nn = 4096;
constexpr int FEAT = 9;            // 1 silu + 8 spline
constexpr int K1   = D * FEAT;     // 6912
constexpr int LDAB = 6912;         // row stride of feat / packed W (elements)
}

typedef _Float16 half8 __attribute__((ext_vector_type(8)));
typedef float f32x4 __attribute__((ext_vector_type(4)));

// global -> LDS direct copy, 16B/lane, LDS dest = wave-uniform base + lane*16
DEV void gld16(const void* g, void* l) {
    __builtin_amdgcn_global_load_lds((__attribute__((address_space(1))) void*)g,
                                     (__attribute__((address_space(3))) void*)l,
                                     16, 0, 0);
}

// bijective XCD swizzle (m204)
DEV int xcd_swz(int id, int nwg) {
    int q = nwg >> 3, r = nwg & 7;
    int xcd = id & 7, pos = id >> 3;
    return (xcd < r ? xcd * (q + 1) : r * (q + 1) + (xcd - r) * q) + pos;
}

// ------- feature eval: silu + 8 cubic B-spline bases (validated r2-r6) ----
DEV void features9(float xv, float* f) {
    f[0] = xv / (1.0f + __expf(-xv));
    float sp = (xv + 2.2f) * 2.5f;
    float fj = floorf(sp);
    int j = (int)fj;
    float u = sp - fj;
    float u2 = u * u, u3 = u2 * u;
    float omu = 1.0f - u;
    float b0 = (1.0f / 6.0f) * omu * omu * omu;
    float b1 = 0.5f * u3 - u2 + (2.0f / 3.0f);
    float b2 = -0.5f * u3 + 0.5f * u2 + 0.5f * u + (1.0f / 6.0f);
    float b3 = (1.0f / 6.0f) * u3;
#pragma unroll
    for (int m = 0; m < 8; ++m) {
        int d = j - m;
        f[1 + m] = (d == 3) ? b0 : (d == 2) ? b1 : (d == 1) ? b2 : (d == 0) ? b3 : 0.0f;
    }
}

// ---------------- LN1: fp32 in -> fp16 out --------------------------------
__global__ __launch_bounds__(256) void ln16_kernel(const float* __restrict__ x,
                                                   const float* __restrict__ g,
                                                   const float* __restrict__ bta,
                                                   _Float16* __restrict__ y) {
    int row = blockIdx.x;
    const float* xr = x + (size_t)row * D;
    _Float16* yr = y + (size_t)row * D;
    int t = threadIdx.x;
    float v[3];
#pragma unroll
    for (int j = 0; j < 3; ++j) v[j] = xr[t + j * 256];
    float s = v[0] + v[1] + v[2];
#pragma unroll
    for (int o = 1; o < 64; o <<= 1) s += __shfl_xor(s, o, 64);
    __shared__ float red[4], red2[4];
    int wid = t >> 6;
    if ((t & 63) == 0) red[wid] = s;
    __syncthreads();
    float mean = (red[0] + red[1] + red[2] + red[3]) * (1.0f / 768.0f);
    float d0 = v[0] - mean, d1 = v[1] - mean, d2 = v[2] - mean;
    float sq = d0 * d0 + d1 * d1 + d2 * d2;
#pragma unroll
    for (int o = 1; o < 64; o <<= 1) sq += __shfl_xor(sq, o, 64);
    if ((t & 63) == 0) red2[wid] = sq;
    __syncthreads();
    float var = (red2[0] + red2[1] + red2[2] + red2[3]) * (1.0f / 768.0f);
    float rstd = rsqrtf(var + 1e-5f);
#pragma unroll
    for (int j = 0; j < 3; ++j) {
        int c = t + j * 256;
        yr[c] = (_Float16)((v[j] - mean) * rstd * g[c] + bta[c]);
    }
}

// ------- LN2 of (x + attn) fused with feature expansion -> feat1 ----------
__global__ __launch_bounds__(256) void ln_feat(const float* __restrict__ xa,
                                               const float* __restrict__ xb,
                                               const float* __restrict__ g,
                                               const float* __restrict__ bta,
                                               _Float16* __restrict__ feat) {
    int row = blockIdx.x;
    const float* xar = xa + (size_t)row * D;
    const float* xbr = xb + (size_t)row * D;
    int t = threadIdx.x;
    float v[3];
#pragma unroll
    for (int j = 0; j < 3; ++j) v[j] = xar[t + j * 256] + xbr[t + j * 256];
    float s = v[0] + v[1] + v[2];
#pragma unroll
    for (int o = 1; o < 64; o <<= 1) s += __shfl_xor(s, o, 64);
    __shared__ float red[4], red2[4];
    __shared__ __align__(16) _Float16 fbuf[K1];
    int wid = t >> 6;
    if ((t & 63) == 0) red[wid] = s;
    __syncthreads();
    float mean = (red[0] + red[1] + red[2] + red[3]) * (1.0f / 768.0f);
    float d0 = v[0] - mean, d1 = v[1] - mean, d2 = v[2] - mean;
    float sq = d0 * d0 + d1 * d1 + d2 * d2;
#pragma unroll
    for (int o = 1; o < 64; o <<= 1) sq += __shfl_xor(sq, o, 64);
    if ((t & 63) == 0) red2[wid] = sq;
    __syncthreads();
    float var = (red2[0] + red2[1] + red2[2] + red2[3]) * (1.0f / 768.0f);
    float rstd = rsqrtf(var + 1e-5f);
#pragma unroll
    for (int j = 0; j < 3; ++j) {
        int c = t + j * 256;
        float y = (v[j] - mean) * rstd * g[c] + bta[c];
        float f[9];
        features9(y, f);
#pragma unroll
        for (int cc = 0; cc < 9; ++cc) fbuf[c * 9 + cc] = (_Float16)f[cc];
    }
    __syncthreads();
    _Float16* dst = feat + (size_t)row * K1;
    for (int i = t; i < K1 / 8; i += 256)
        *(half8*)(dst + i * 8) = *(const half8*)&fbuf[i * 8];
}

// ------- feature expansion of h1 chunk (768 cols) -> featbuf --------------
__global__ __launch_bounds__(256) void feat2_chunk(const _Float16* __restrict__ h1,
                                                   int c0,
                                                   _Float16* __restrict__ feat) {
    int row = blockIdx.x;
    int t = threadIdx.x;
    __shared__ __align__(16) _Float16 fbuf[K1];
    const _Float16* src = h1 + (size_t)row * F + c0;
#pragma unroll
    for (int j = 0; j < 3; ++j) {
        int ic = t + j * 256;
        float y = (float)src[ic];
        float f[9];
        features9(y, f);
#pragma unroll
        for (int cc = 0; cc < 9; ++cc) fbuf[ic * 9 + cc] = (_Float16)f[cc];
    }
    __syncthreads();
    _Float16* dst = feat + (size_t)row * K1;
    for (int i = t; i < K1 / 8; i += 256)
        *(half8*)(dst + i * 8) = *(const half8*)&fbuf[i * 8];
}

// ------- pack KAN weights: Wp[o][ic*9+c] = {base_w, spline*scaler} fp16 ---
__global__ __launch_bounds__(256) void prep_w(const float* __restrict__ bw,
                                              const float* __restrict__ sw,
                                              const float* __restrict__ scal,
                                              _Float16* __restrict__ Wp,
                                              int INfull, int c0) {
    int o = blockIdx.y;
    int ic = blockIdx.x * 256 + threadIdx.x;
    size_t idx = (size_t)o * INfull + c0 + ic;
    float bwv = bw[idx];
    float sc  = scal[idx];
    float4 s0 = *(const float4*)(sw + idx * 8);
    float4 s1 = *(const float4*)(sw + idx * 8 + 4);
    _Float16* dst = Wp + ((size_t)o * 768 + ic) * 9;
    dst[0] = (_Float16)bwv;
    dst[1] = (_Float16)(s0.x * sc);
    dst[2] = (_Float16)(s0.y * sc);
    dst[3] = (_Float16)(s0.z * sc);
    dst[4] = (_Float16)(s0.w * sc);
    dst[5] = (_Float16)(s1.x * sc);
    dst[6] = (_Float16)(s1.y * sc);
    dst[7] = (_Float16)(s1.z * sc);
    dst[8] = (_Float16)(s1.w * sc);
}

// ---------------- prep: qkv weights fp32 -> fp16 --------------------------
__global__ __launch_bounds__(256) void prep_qkv(const float* __restrict__ wq,
                                                const float* __restrict__ wk,
                                                const float* __restrict__ wv,
                                                _Float16* __restrict__ Wh) {
    int idx = blockIdx.x * 256 + threadIdx.x;
    const int per = D * D;
    if (idx >= 3 * per) return;
    int z = idx / per, rem = idx - z * per;
    const float* w = (z == 0) ? wq : (z == 1) ? wk : wv;
    Wh[idx] = (_Float16)w[rem];
}

// ---------------- QKV via fp16 MFMA, writes (B,H,S,DK) fp16 ---------------
__global__ __launch_bounds__(256, 2) void qkv16(const _Float16* __restrict__ Xh,
                                                const _Float16* __restrict__ Wh,
                                                const float* __restrict__ bq,
                                                const float* __restrict__ bk,
                                                const float* __restrict__ bv,
                                                _Float16* __restrict__ q,
                                                _Float16* __restrict__ k,
                                                _Float16* __restrict__ v) {
    int z = blockIdx.z;
    const _Float16* W = Wh + (size_t)z * D * D;
    const float* bias = (z == 0) ? bq : (z == 1) ? bk : bv;
    _Float16* out     = (z == 0) ? q  : (z == 1) ? k  : v;

    __shared__ __align__(16) _Float16 As[128][72];
    int t = threadIdx.x;
    int l = t & 63, w = t >> 6;
    int m0 = blockIdx.y * 128, o0 = blockIdx.x * 128;
    int wr = (w >> 1) * 64, wc = (w & 1) * 64;
    int lm = l & 15, lk = (l >> 4) * 8;
    int srow = t >> 1, sh = t & 1;

    f32x4 acc[4][4];
#pragma unroll
    for (int a = 0; a < 4; ++a)
#pragma unroll
        for (int b = 0; b < 4; ++b)
#pragma unroll
            for (int c = 0; c < 4; ++c) acc[a][b][c] = 0.0f;

    const _Float16* bp0 = W + (size_t)(o0 + wc + lm) * D + lk;

    for (int kt = 0; kt < D / 64; ++kt) {
        half8 ar[4];
#pragma unroll
        for (int i = 0; i < 4; ++i)
            ar[i] = *(const half8*)(Xh + (size_t)(m0 + srow) * D + kt * 64 + sh * 32 + i * 8);
        __syncthreads();
#pragma unroll
        for (int i = 0; i < 4; ++i)
            *(half8*)&As[srow][sh * 32 + i * 8] = ar[i];
        __syncthreads();
        half8 bfr[2][4];
#pragma unroll
        for (int kc = 0; kc < 2; ++kc)
#pragma unroll
            for (int nf = 0; nf < 4; ++nf)
                bfr[kc][nf] = *(const half8*)(bp0 + (size_t)nf * 16 * D + kt * 64 + kc * 32);
#pragma unroll
        for (int kc = 0; kc < 2; ++kc) {
            half8 a_[4];
#pragma unroll
            for (int mf = 0; mf < 4; ++mf)
                a_[mf] = *(const half8*)&As[wr + mf * 16 + lm][kc * 32 + lk];
#pragma unroll
            for (int mf = 0; mf < 4; ++mf)
#pragma unroll
                for (int nf = 0; nf < 4; ++nf)
                    acc[mf][nf] = __builtin_amdgcn_mfma_f32_16x16x32_f16(a_[mf], bfr[kc][nf], acc[mf][nf], 0, 0, 0);
        }
    }
    int r0 = m0 + wr + (l >> 4) * 4;
    int c0 = o0 + wc + lm;
#pragma unroll
    for (int mf = 0; mf < 4; ++mf)
#pragma unroll
        for (int nf = 0; nf < 4; ++nf) {
            int col = c0 + nf * 16;
            int hh = col >> 6, dd = col & 63;
            float bv_ = bias[col];
#pragma unroll
            for (int r = 0; r < 4; ++r) {
                int n = r0 + mf * 16 + r;
                int b = n >> 11, ss = n & 2047;
                out[(((size_t)(b * Hh + hh) * S + ss) * DK + dd)] = (_Float16)(acc[mf][nf][r] + bv_);
            }
        }
}

// ---------------- Flash attention, fp16 MFMA (as round 6) -----------------
__global__ __launch_bounds__(512) void attn16(const _Float16* __restrict__ q16,
                                              const _Float16* __restrict__ k16,
                                              const _Float16* __restrict__ v16,
                                              float* __restrict__ attno) {
    int nwg = gridDim.x * gridDim.y;
    int id = blockIdx.x + gridDim.x * blockIdx.y;
    int id2 = xcd_swz(id, nwg);
    int bh = id2 / gridDim.x;
    int q0 = (id2 % gridDim.x) * 128;

    int t = threadIdx.x;
    int l = t & 63, w = t >> 6;
    int lm = l & 15, lk = (l >> 4) * 8;
    int wr = w * 16;

    __shared__ __align__(16) _Float16 Qs[128][72];
    __shared__ __align__(16) _Float16 Ps[128][72];
    __shared__ __align__(16) _Float16 Ks[64][72];
    __shared__ __align__(16) _Float16 Vt[64][72];

    const _Float16* qb = q16 + ((size_t)bh * S + q0) * DK;
    const _Float16* kb = k16 + (size_t)bh * S * DK;
    const _Float16* vb = v16 + (size_t)bh * S * DK;

    {
        int row = t >> 2, dg = t & 3;
        half8 h0 = *(const half8*)(qb + row * DK + dg * 16);
        half8 h1 = *(const half8*)(qb + row * DK + dg * 16 + 8);
#pragma unroll
        for (int j = 0; j < 8; ++j) { h0[j] = h0[j] * (_Float16)0.125f; h1[j] = h1[j] * (_Float16)0.125f; }
        *(half8*)&Qs[row][dg * 16] = h0;
        *(half8*)&Qs[row][dg * 16 + 8] = h1;
    }

    float m_[4], l_[4];
    f32x4 oacc[4];
#pragma unroll
    for (int r = 0; r < 4; ++r) { m_[r] = -INFINITY; l_[r] = 0.0f; }
#pragma unroll
    for (int nf = 0; nf < 4; ++nf)
#pragma unroll
        for (int r = 0; r < 4; ++r) oacc[nf][r] = 0.0f;

    for (int kt = 0; kt < S / 64; ++kt) {
        __syncthreads();
        {
            int tt = t & 255;
            int key = tt & 63, dg = tt >> 6;
            if (t < 256) {
                const _Float16* kr = kb + ((size_t)kt * 64 + key) * DK + dg * 16;
                half8 k0 = *(const half8*)(kr);
                half8 k1 = *(const half8*)(kr + 8);
                *(half8*)&Ks[key][dg * 16] = k0;
                *(half8*)&Ks[key][dg * 16 + 8] = k1;
            } else {
                const _Float16* vr = vb + ((size_t)kt * 64 + key) * DK + dg * 16;
                half8 v0 = *(const half8*)(vr);
                half8 v1 = *(const half8*)(vr + 8);
#pragma unroll
                for (int j = 0; j < 8; ++j) {
                    Vt[dg * 16 + j][key] = v0[j];
                    Vt[dg * 16 + 8 + j][key] = v1[j];
                }
            }
        }
        __syncthreads();

        f32x4 sc[4];
#pragma unroll
        for (int nf = 0; nf < 4; ++nf)
#pragma unroll
            for (int r = 0; r < 4; ++r) sc[nf][r] = 0.0f;
        __builtin_amdgcn_s_setprio(1);
#pragma unroll
        for (int kc = 0; kc < 2; ++kc) {
            half8 aq = *(const half8*)&Qs[wr + lm][kc * 32 + lk];
#pragma unroll
            for (int nf = 0; nf < 4; ++nf) {
                half8 bk8 = *(const half8*)&Ks[nf * 16 + lm][kc * 32 + lk];
                sc[nf] = __builtin_amdgcn_mfma_f32_16x16x32_f16(aq, bk8, sc[nf], 0, 0, 0);
            }
        }
        __builtin_amdgcn_s_setprio(0);
        float pmax[4];
#pragma unroll
        for (int r = 0; r < 4; ++r) {
            pmax[r] = fmaxf(fmaxf(sc[0][r], sc[1][r]), fmaxf(sc[2][r], sc[3][r]));
#pragma unroll
            for (int mk = 1; mk < 16; mk <<= 1)
                pmax[r] = fmaxf(pmax[r], __shfl_xor(pmax[r], mk, 64));
        }
        float corr[4], rs[4];
#pragma unroll
        for (int r = 0; r < 4; ++r) {
            float mnew = fmaxf(m_[r], pmax[r]);
            corr[r] = __expf(m_[r] - mnew);
            m_[r] = mnew;
            rs[r] = 0.0f;
        }
#pragma unroll
        for (int nf = 0; nf < 4; ++nf)
#pragma unroll
            for (int r = 0; r < 4; ++r) {
                float p = __expf(sc[nf][r] - m_[r]);
                sc[nf][r] = p;
                rs[r] += p;
            }
#pragma unroll
        for (int r = 0; r < 4; ++r) {
#pragma unroll
            for (int mk = 1; mk < 16; mk <<= 1)
                rs[r] += __shfl_xor(rs[r], mk, 64);
            l_[r] = l_[r] * corr[r] + rs[r];
        }
        int pr = wr + (l >> 4) * 4;
#pragma unroll
        for (int nf = 0; nf < 4; ++nf)
#pragma unroll
            for (int r = 0; r < 4; ++r)
                Ps[pr + r][nf * 16 + lm] = (_Float16)sc[nf][r];
#pragma unroll
        for (int nf = 0; nf < 4; ++nf)
#pragma unroll
            for (int r = 0; r < 4; ++r) oacc[nf][r] *= corr[r];
        __builtin_amdgcn_s_setprio(1);
#pragma unroll
        for (int kc = 0; kc < 2; ++kc) {
            half8 ap = *(const half8*)&Ps[wr + lm][kc * 32 + lk];
#pragma unroll
            for (int nf = 0; nf < 4; ++nf) {
                half8 bv8 = *(const half8*)&Vt[nf * 16 + lm][kc * 32 + lk];
                oacc[nf] = __builtin_amdgcn_mfma_f32_16x16x32_f16(ap, bv8, oacc[nf], 0, 0, 0);
            }
        }
        __builtin_amdgcn_s_setprio(0);
    }
    int b = bh / Hh, hh = bh % Hh;
    int pr = wr + (l >> 4) * 4;
#pragma unroll
    for (int r = 0; r < 4; ++r) {
        float inv = 1.0f / l_[r];
        float* orow = attno + ((size_t)b * S + q0 + pr + r) * D + hh * DK;
#pragma unroll
        for (int nf = 0; nf < 4; ++nf)
            orow[nf * 16 + lm] = oacc[nf][r] * inv;
    }
}

// ----- KAN GEMM: counted-vmcnt double-buffered pipeline (T3/T4/T5 + swz) --
// C = A * B^T; A:(M x 6912), B:(O x 6912) fp16 row-major. 128x128 tile,
// 4 waves x (64x64), BK=64. Per wave per K-tile: 8 global_load_lds.
// Schedule per tile t: issue stage(t+1) -> vmcnt(8) [t's 8 oldest done,
// t+1's 8 stay in flight] -> raw barrier -> MFMA -> raw barrier.
// LDS 16B-chunk XOR swizzle (chunk ^= row&7): pre-swizzled GLOBAL source +
// swizzled read, linear LDS dest (rule 21).
template <int KS, bool TOF16>
__global__ __launch_bounds__(256, 2) void kan_gemm(const _Float16* __restrict__ A,
                                                   const _Float16* __restrict__ B,
                                                   _Float16* __restrict__ out16,
                                                   float* __restrict__ out32,
                                                   int O, int accum) {
    __shared__ __align__(16) _Float16 Al[2][128 * 64];
    __shared__ __align__(16) _Float16 Bl[2][128 * 64];
    int t = threadIdx.x;
    int l = t & 63, w = t >> 6;
    int m0 = blockIdx.y * 128, o0 = blockIdx.x * 128;
    int slot = blockIdx.z;
    int wr = (w >> 1) * 64, wc = (w & 1) * 64;
    int lm = l & 15, lkq = l >> 4;           // frag col-chunk quarter 0..3

    const _Float16* Ab = A + (size_t)slot * KS * 64;
    const _Float16* Bb = B + (size_t)slot * KS * 64;
    int srow = l >> 3;                        // staging row-in-window 0..7
    int schunk = ((l & 7) ^ srow) * 8;        // swizzled source col (halves)

    f32x4 acc[4][4];
#pragma unroll
    for (int a = 0; a < 4; ++a)
#pragma unroll
        for (int b = 0; b < 4; ++b)
#pragma unroll
            for (int c = 0; c < 4; ++c) acc[a][b][c] = 0.0f;

    // ---- stage tile kt into buffer bu (8 gld/wave) ----
    auto stage = [&](int kt, int bu) {
        size_t kofs = (size_t)kt * 64 + schunk;
#pragma unroll
        for (int j = 0; j < 4; ++j) {
            int row = w * 32 + j * 8;
            gld16(Ab + (size_t)(m0 + row + srow) * LDAB + kofs, &Al[bu][row * 64]);
            gld16(Bb + (size_t)(o0 + row + srow) * LDAB + kofs, &Bl[bu][row * 64]);
        }
    };

    stage(0, 0);   // prologue: tile 0 in flight (8/wave outstanding)

    for (int kt = 0; kt < KS; ++kt) {
        int cur = kt & 1;
        if (kt + 1 < KS) {
            stage(kt + 1, cur ^ 1);           // 16/wave outstanding
            asm volatile("s_waitcnt vmcnt(8)" ::: "memory");   // tile kt landed
        } else {
            asm volatile("s_waitcnt vmcnt(0)" ::: "memory");   // last tile drain
        }
        __builtin_amdgcn_sched_barrier(0);
        __builtin_amdgcn_s_barrier();         // all waves' tile-kt loads landed
        __builtin_amdgcn_sched_barrier(0);

        const _Float16* Ac = &Al[cur][0];
        const _Float16* Bc = &Bl[cur][0];
#pragma unroll
        for (int kc = 0; kc < 2; ++kc) {
            int cw = (((kc * 4 + lkq) ^ (lm & 7)) * 8);   // swizzled read col
            half8 af[4], bf[4];
#pragma unroll
            for (int mf = 0; mf < 4; ++mf)
                af[mf] = *(const half8*)&Ac[(wr + mf * 16 + lm) * 64 + cw];
#pragma unroll
            for (int nf = 0; nf < 4; ++nf)
                bf[nf] = *(const half8*)&Bc[(wc + nf * 16 + lm) * 64 + cw];
            __builtin_amdgcn_s_setprio(1);
#pragma unroll
            for (int mf = 0; mf < 4; ++mf)
#pragma unroll
                for (int nf = 0; nf < 4; ++nf)
                    acc[mf][nf] = __builtin_amdgcn_mfma_f32_16x16x32_f16(af[mf], bf[nf], acc[mf][nf], 0, 0, 0);
            __builtin_amdgcn_s_setprio(0);
        }
        __builtin_amdgcn_sched_barrier(0);
        __builtin_amdgcn_s_barrier();         // all reads of buf[cur] done
        __builtin_amdgcn_sched_barrier(0);
    }

    int r0 = m0 + wr + (l >> 4) * 4;
    int c0 = o0 + wc + lm;
#pragma unroll
    for (int mf = 0; mf < 4; ++mf)
#pragma unroll
        for (int nf = 0; nf < 4; ++nf)
#pragma unroll
            for (int r = 0; r < 4; ++r) {
                int row = r0 + mf * 16 + r;
                int col = c0 + nf * 16;
                if constexpr (TOF16) {
                    out16[(size_t)row * O + col] = (_Float16)acc[mf][nf][r];
                } else {
                    float* po = out32 + ((size_t)slot * Nn + row) * O + col;
                    float vv = acc[mf][nf][r];
                    if (accum) vv += *po;
                    *po = vv;
                }
            }
}

// ---------------- final reduce: 4 partials + x + attn ---------------------
__global__ __launch_bounds__(256) void reduce4(const float* __restrict__ part,
                                               const float* __restrict__ x,
                                               const float* __restrict__ attno,
                                               float* __restrict__ out) {
    int i = blockIdx.x * 256 + threadIdx.x;
    const size_t ND4 = (size_t)Nn * D / 4;
    if (i >= (int)ND4) return;
    const float4* p0 = (const float4*)part;
    const float4* p1 = p0 + ND4;
    const float4* p2 = p1 + ND4;
    const float4* p3 = p2 + ND4;
    float4 a = p0[i], b = p1[i], c = p2[i], d = p3[i];
    float4 xe = ((const float4*)x)[i], at = ((const float4*)attno)[i];
    float4 o;
    o.x = a.x + b.x + c.x + d.x + xe.x + at.x;
    o.y = a.y + b.y + c.y + d.y + xe.y + at.y;
    o.z = a.z + b.z + c.z + d.z + xe.z + at.z;
    o.w = a.w + b.w + c.w + d.w + xe.w + at.w;
    ((float4*)out)[i] = o;
}

// ---------------- launcher -------------------------------------------------
extern "C" void kernel_launch(void* const* d_in, const int* in_sizes, int n_in,
                              void* d_out, int out_size, void* d_ws, size_t ws_size,
                              hipStream_t stream) {
    const float* x    = (const float*)d_in[0];
    const float* ln1g = (const float*)d_in[2];
    const float* ln1b = (const float*)d_in[3];
    const float* wq   = (const float*)d_in[4];
    const float* bq   = (const float*)d_in[5];
    const float* wk   = (const float*)d_in[6];
    const float* bk   = (const float*)d_in[7];
    const float* wv   = (const float*)d_in[8];
    const float* bv   = (const float*)d_in[9];
    const float* ln2g = (const float*)d_in[10];
    const float* ln2b = (const float*)d_in[11];
    const float* bw1  = (const float*)d_in[12];
    const float* sw1  = (const float*)d_in[13];
    const float* sc1  = (const float*)d_in[14];
    const float* bw2  = (const float*)d_in[15];
    const float* sw2  = (const float*)d_in[16];
    const float* sc2  = (const float*)d_in[17];

    const size_t ND = (size_t)Nn * D;
    char* base = (char*)d_ws;
    _Float16* featbuf = (_Float16*)base;                              // Nn*K1 = 56.6MB
    _Float16* q16 = featbuf;
    _Float16* k16 = featbuf + ND;
    _Float16* v16 = featbuf + 2 * ND;
    char* p = base + (size_t)Nn * K1 * 2;
    float* attno = (float*)p;            p += ND * 4;                 // 12.58MB
    _Float16* h1h = (_Float16*)p;        p += (size_t)Nn * F * 2;     // 25.17MB
    char* R3 = p;
    _Float16* Wp1 = (_Float16*)R3;                                    // 42.5MB
    _Float16* xnh = (_Float16*)(R3 + 42467328);
    _Float16* Wh  = (_Float16*)(R3 + 48758784);
    float* part   = (float*)R3;                                       // 50.3MB (after L1)
    char* R4 = R3 + 52297728;
    _Float16* Wp2c = (_Float16*)R4;                                   // 10.6MB

    // 1. LN1 -> fp16
    ln16_kernel<<<Nn, 256, 0, stream>>>(x, ln1g, ln1b, xnh);
    // 2. qkv weights fp16
    prep_qkv<<<(3 * D * D + 255) / 256, 256, 0, stream>>>(wq, wk, wv, Wh);
    // 3. QKV -> fp16 (B,H,S,DK)
    qkv16<<<dim3(D / 128, Nn / 128, 3), 256, 0, stream>>>(xnh, Wh, bq, bk, bv, q16, k16, v16);
    // 4. flash attention (MFMA, 128-row tiles) -> attno fp32
    attn16<<<dim3(S / 128, 2 * Hh), 512, 0, stream>>>(q16, k16, v16, attno);
    // 5. pack layer-1 weights
    prep_w<<<dim3(3, F), 256, 0, stream>>>(bw1, sw1, sc1, Wp1, D, 0);
    // 6. LN2(x+attn) + feature expansion -> feat1 (overwrites q/k/v)
    ln_feat<<<Nn, 256, 0, stream>>>(x, attno, ln2g, ln2b, featbuf);
    // 7. KAN layer 1 GEMM: (4096x6912) x (3072x6912)^T -> h1h fp16
    kan_gemm<108, true><<<dim3(F / 128, Nn / 128, 1), 256, 0, stream>>>(
        featbuf, Wp1, h1h, nullptr, F, 0);
    // 8. KAN layer 2 in 4 K-chunks; split-K z=4 within chunk
    for (int c = 0; c < 4; ++c) {
        prep_w<<<dim3(3, D), 256, 0, stream>>>(bw2, sw2, sc2, Wp2c, F, c * 768);
        feat2_chunk<<<Nn, 256, 0, stream>>>(h1h, c * 768, featbuf);
        kan_gemm<27, false><<<dim3(D / 128, Nn / 128, 4), 256, 0, stream>>>(
            featbuf, Wp2c, nullptr, part, D, c > 0);
    }
    // 9. partials + residuals -> out
    reduce4<<<(int)(ND / 4 / 256), 256, 0, stream>>>(part, x, attno, (float*)d_out);
}